// Round 13
// baseline (210.515 us; speedup 1.0000x reference)
//
#include <hip/hip_runtime.h>
#include <math.h>

#define NN   4096
#define DD   512
#define TWON 8192
#define KSLICE 8

typedef _Float16 half_t;
typedef unsigned short u16;
using half8  = __attribute__((ext_vector_type(8))) half_t;
using short8 = __attribute__((ext_vector_type(8))) short;
using f32x4  = __attribute__((ext_vector_type(4))) float;

__device__ __forceinline__ u16 f2bf(float f) {
    unsigned u = __float_as_uint(f);
    u += 0x7fffu + ((u >> 16) & 1u);
    return (u16)(u >> 16);
}
__device__ __forceinline__ float bf2f(u16 h) {
    return __uint_as_float(((unsigned)h) << 16);
}
__device__ __forceinline__ void gl16(const void* g, void* l) {
    __builtin_amdgcn_global_load_lds(
        (const __attribute__((address_space(1))) void*)g,
        (__attribute__((address_space(3))) void*)l, 16, 0, 0);
}
__device__ __forceinline__ f32x4 mfma16h(half8 a, half8 b, f32x4 c) {
    return __builtin_amdgcn_mfma_f32_16x16x32_f16(a, b, c, 0, 0, 0);
}
__device__ __forceinline__ f32x4 mfma16b(short8 a, short8 b, f32x4 c) {
    return __builtin_amdgcn_mfma_f32_16x16x32_bf16(a, b, c, 0, 0, 0);
}

// ---------------- prep: b=[y;x] -> f16 + norms nb[8192]
__global__ __launch_bounds__(64)
void prep_k(const float* __restrict__ x, const float* __restrict__ y,
            half_t* __restrict__ bhi, float* __restrict__ nb) {
    int r = blockIdx.x;           // 0..8191
    int l = threadIdx.x;          // 64
    const float* src = (r < NN) ? (y + (size_t)r * DD) : (x + (size_t)(r - NN) * DD);
    float4 v0 = *reinterpret_cast<const float4*>(src + l * 8);
    float4 v1 = *reinterpret_cast<const float4*>(src + l * 8 + 4);
    float e[8] = {v0.x, v0.y, v0.z, v0.w, v1.x, v1.y, v1.z, v1.w};
    float s = 0.f;
    half8 h;
    #pragma unroll
    for (int q = 0; q < 8; ++q) {
        s += e[q] * e[q];
        h[q] = (half_t)e[q];
    }
    *reinterpret_cast<half8*>(bhi + (size_t)r * DD + l * 8) = h;
    #pragma unroll
    for (int off = 32; off; off >>= 1) s += __shfl_down(s, off);
    if (l == 0) nb[r] = s;
}

// ---------------- b2t: b2t[d][k] = k<N ? y[k][d] : -x[k-N][d]  (bf16, 512x8192)
__global__ __launch_bounds__(256)
void b2t_k(const float* __restrict__ x, const float* __restrict__ y, u16* __restrict__ b2t) {
    __shared__ float tl[32][33];
    int k0 = blockIdx.x * 32, d0 = blockIdx.y * 32;
    int tx = threadIdx.x, ty = threadIdx.y;   // (32,8)
    const float* src = (k0 < NN) ? y : x;
    int row0 = (k0 < NN) ? k0 : (k0 - NN);
    #pragma unroll
    for (int j = 0; j < 4; ++j)
        tl[ty + 8 * j][tx] = src[(size_t)(row0 + ty + 8 * j) * DD + d0 + tx];
    __syncthreads();
    float sgn = (k0 < NN) ? 1.f : -1.f;
    #pragma unroll
    for (int j = 0; j < 4; ++j) {
        float v = tl[tx][ty + 8 * j] * sgn;
        b2t[(size_t)(d0 + ty + 8 * j) * TWON + k0 + tx] = f2bf(v);
    }
}

// ---------------- GEMM1: f16 MFMA + logits; shared-C epilogue (proven r12);
// stores E=exp(l-C) bf16, Ct per tile, rpm/rps row partials, cpm/cps col partials.
__global__ __launch_bounds__(256)
void gemm1_k(const half_t* __restrict__ bhi,
             const float* __restrict__ nb, u16* __restrict__ Ef,
             float* __restrict__ Ct,
             float* __restrict__ rpm, float* __restrict__ rps,
             float* __restrict__ cpm, float* __restrict__ cps) {
    __shared__ unsigned char lds[32768]; // Ahi@0 Bhi@16K, each 128x64 f16 swizzled
    const int t = threadIdx.x;
    const int wave = t >> 6, lane = t & 63;
    const int i0 = blockIdx.y * 128, j0 = blockIdx.x * 128;
    const int wm = (wave >> 1) * 64, wn = (wave & 1) * 64;
    const half_t* ahig = bhi + (size_t)NN * DD;  // x rows are b rows 4096..8191
    f32x4 acc[4][4] = {};
    for (int k0 = 0; k0 < DD; k0 += 64) {
        __syncthreads();
        #pragma unroll
        for (int q = 0; q < 4; ++q) {
            const int dbase = (wave * 4 + q) * 1024;
            const int p  = dbase + lane * 16;
            const int r  = p >> 7;
            const int cb = (p & 127) ^ ((r & 7) << 4);
            const size_t offA = (size_t)(i0 + r) * DD + k0 + (cb >> 1);
            const size_t offB = (size_t)(j0 + r) * DD + k0 + (cb >> 1);
            gl16(ahig + offA, lds + dbase);
            gl16(bhi  + offB, lds + 16384 + dbase);
        }
        asm volatile("s_waitcnt vmcnt(0)" ::: "memory");
        __builtin_amdgcn_sched_barrier(0);
        __syncthreads();
        #pragma unroll
        for (int kk = 0; kk < 2; ++kk) {
            half8 ah[4];
            #pragma unroll
            for (int m = 0; m < 4; ++m) {
                const int row = wm + m * 16 + (lane & 15);
                const int off = row * 128 + ((kk * 64 + (lane >> 4) * 16) ^ ((row & 7) << 4));
                ah[m] = *reinterpret_cast<const half8*>(lds + off);
            }
            #pragma unroll
            for (int n = 0; n < 4; ++n) {
                const int row = wn + n * 16 + (lane & 15);
                const int off = row * 128 + ((kk * 64 + (lane >> 4) * 16) ^ ((row & 7) << 4));
                half8 bh = *reinterpret_cast<const half8*>(lds + 16384 + off);
                #pragma unroll
                for (int m = 0; m < 4; ++m)
                    acc[m][n] = mfma16h(ah[m], bh, acc[m][n]);
            }
        }
    }
    // ---- pass 1: acc -> logits, track thread max
    float nbj[4];
    #pragma unroll
    for (int n = 0; n < 4; ++n) nbj[n] = nb[j0 + wn + n * 16 + (lane & 15)];
    float tmax = -3.0e38f;
    #pragma unroll
    for (int m = 0; m < 4; ++m) {
        #pragma unroll
        for (int r4 = 0; r4 < 4; ++r4) {
            const int i = i0 + wm + m * 16 + (lane >> 4) * 4 + r4;
            const float nxi = nb[NN + i];
            #pragma unroll
            for (int n = 0; n < 4; ++n) {
                const int j = j0 + wn + n * 16 + (lane & 15);
                float sq = nxi + nbj[n] - 2.0f * acc[m][n][r4];
                float lg = -10.0f * sqrtf(fmaxf(sq, 1e-12f));
                if (j == i + NN) lg = -1e7f;
                acc[m][n][r4] = lg;
                tmax = fmaxf(tmax, lg);
            }
        }
    }
    // ---- block-wide shared max C
    #pragma unroll
    for (int off = 1; off < 64; off <<= 1) tmax = fmaxf(tmax, __shfl_xor(tmax, off));
    __syncthreads();
    float* red = reinterpret_cast<float*>(lds);
    if (lane == 0) red[wave] = tmax;
    __syncthreads();
    const float C = fmaxf(fmaxf(red[0], red[1]), fmaxf(red[2], red[3]));
    __syncthreads();
    if (t == 0) Ct[blockIdx.y * 64 + blockIdx.x] = C;
    // ---- pass 2: single exp; store bf16 E; row/col partial sums (pure adds)
    float rs[16] = {}, cs[4] = {};
    #pragma unroll
    for (int m = 0; m < 4; ++m)
        #pragma unroll
        for (int r4 = 0; r4 < 4; ++r4) {
            const int idx = m * 4 + r4;
            const int i = i0 + wm + m * 16 + (lane >> 4) * 4 + r4;
            #pragma unroll
            for (int n = 0; n < 4; ++n) {
                const int j = j0 + wn + n * 16 + (lane & 15);
                float e = __expf(acc[m][n][r4] - C);
                Ef[(size_t)i * TWON + j] = f2bf(e);
                rs[idx] += e;
                cs[n]   += e;
            }
        }
    #pragma unroll
    for (int off = 1; off < 16; off <<= 1) {
        #pragma unroll
        for (int idx = 0; idx < 16; ++idx) rs[idx] += __shfl_xor(rs[idx], off);
    }
    #pragma unroll
    for (int off = 16; off < 64; off <<= 1) {
        #pragma unroll
        for (int n = 0; n < 4; ++n) cs[n] += __shfl_xor(cs[n], off);
    }
    // ---- cross-wave combine: rows red[0..255], cols red[256..511]
    if ((lane & 15) == 0) {
        #pragma unroll
        for (int m = 0; m < 4; ++m)
            #pragma unroll
            for (int r4 = 0; r4 < 4; ++r4) {
                const int r = wm + m * 16 + (lane >> 4) * 4 + r4;
                red[(wave & 1) * 128 + r] = rs[m * 4 + r4];
            }
    }
    if (lane < 16) {
        #pragma unroll
        for (int n = 0; n < 4; ++n) {
            const int c = wn + n * 16 + lane;
            red[256 + (wave >> 1) * 128 + c] = cs[n];
        }
    }
    __syncthreads();
    if (t < 128) {
        float S = red[t] + red[128 + t];
        rpm[(size_t)blockIdx.x * NN + i0 + t] = C;
        rps[(size_t)blockIdx.x * NN + i0 + t] = S;
    } else {
        const int c = t - 128;
        float S = red[256 + c] + red[384 + c];
        cpm[(size_t)blockIdx.y * TWON + j0 + c] = C;
        cps[(size_t)blockIdx.y * TWON + j0 + c] = S;
    }
}

// ---------------- combine row partials (64 j-tiles, online) -> rm, rrs
__global__ __launch_bounds__(256)
void row_comb_k(const float* __restrict__ rpm, const float* __restrict__ rps,
                float* __restrict__ rm, float* __restrict__ rrs) {
    int i = blockIdx.x * 256 + threadIdx.x;
    float M = -3.0e38f;
    for (int tt = 0; tt < TWON / 128; ++tt) M = fmaxf(M, rpm[(size_t)tt * NN + i]);
    float S = 0.f;
    for (int tt = 0; tt < TWON / 128; ++tt)
        S += rps[(size_t)tt * NN + i] * __expf(rpm[(size_t)tt * NN + i] - M);
    rm[i] = M; rrs[i] = rsqrtf(S);
}

// ---------------- combine col partials (32 i-tiles) -> Pj = -cm/2 + ln(rcs)
__global__ __launch_bounds__(256)
void col_comb_k(const float* __restrict__ cpm, const float* __restrict__ cps,
                float* __restrict__ Pj) {
    int j = blockIdx.x * 256 + threadIdx.x;
    float M = -3.0e38f;
    for (int tt = 0; tt < NN / 128; ++tt) M = fmaxf(M, cpm[(size_t)tt * TWON + j]);
    float S = 0.f;
    for (int tt = 0; tt < NN / 128; ++tt)
        S += cps[(size_t)tt * TWON + j] * __expf(cpm[(size_t)tt * TWON + j] - M);
    Pj[j] = -0.5f * M - 0.5f * logf(S);    // = -cm/2 + ln(rcs)
}

// ---------------- GEMM2: split-K(8), fused-transform A, DEPTH-2 two-regset
// prefetch (B frags issued FIRST each phase; A-prefetch after — in-order vmcnt
// retirement then never drains the A loads). f16 partials.
__global__ __launch_bounds__(512, 4)
void gemm2_k(const u16* __restrict__ Ef, const u16* __restrict__ b2t,
             const float* __restrict__ Ct, const float* __restrict__ rm,
             const float* __restrict__ Pj, const float* __restrict__ rrs,
             half_t* __restrict__ part) {
    __shared__ unsigned char lds[16384];   // 2 x (64x64 bf16 A tile, swizzled)
    const int t = threadIdx.x;
    const int wave = t >> 6, lane = t & 63;
    const int sw = blockIdx.x;             // 0..511
    const int kslice = sw & 7;             // one kslice per XCD
    const int i0 = (sw >> 3) * 64;
    const int ib = (sw >> 3) >> 1;         // gemm1 128-row tile index
    const int kbase = kslice * (TWON / KSLICE);   // *1024
    const int wn = wave * 64;
    const int sr = t >> 3;          // staging row 0..63
    const int kc = (t & 7) * 8;     // staging k-offset (elements)
    const int awbyte = sr * 128 + ((kc * 2) ^ ((sr & 7) << 4));
    const int NT = (TWON / KSLICE) / 64;   // 16 (even)
    const float rmh = 0.5f * rm[i0 + sr];
    f32x4 acc[4][4] = {};
    // two named prefetch register sets (static indexing — rule #20)
    short8 aE_A, aE_B;
    float4 pA0, pA1, pB0, pB1;
    float argA, argB;
    auto LOADA_A = [&](int it) {
        const int k = kbase + it * 64 + kc;
        aE_A = *reinterpret_cast<const short8*>(Ef + (size_t)(i0 + sr) * TWON + k);
        pA0 = *reinterpret_cast<const float4*>(Pj + k);
        pA1 = *reinterpret_cast<const float4*>(Pj + k + 4);
        argA = Ct[ib * 64 + ((kbase + it * 64) >> 7)] - rmh;
    };
    auto LOADA_B = [&](int it) {
        const int k = kbase + it * 64 + kc;
        aE_B = *reinterpret_cast<const short8*>(Ef + (size_t)(i0 + sr) * TWON + k);
        pB0 = *reinterpret_cast<const float4*>(Pj + k);
        pB1 = *reinterpret_cast<const float4*>(Pj + k + 4);
        argB = Ct[ib * 64 + ((kbase + it * 64) >> 7)] - rmh;
    };
    auto STOREA_A = [&](int buf) {
        short8 g;
        g[0] = (short)f2bf(bf2f((u16)aE_A[0]) * __expf(argA + pA0.x));
        g[1] = (short)f2bf(bf2f((u16)aE_A[1]) * __expf(argA + pA0.y));
        g[2] = (short)f2bf(bf2f((u16)aE_A[2]) * __expf(argA + pA0.z));
        g[3] = (short)f2bf(bf2f((u16)aE_A[3]) * __expf(argA + pA0.w));
        g[4] = (short)f2bf(bf2f((u16)aE_A[4]) * __expf(argA + pA1.x));
        g[5] = (short)f2bf(bf2f((u16)aE_A[5]) * __expf(argA + pA1.y));
        g[6] = (short)f2bf(bf2f((u16)aE_A[6]) * __expf(argA + pA1.z));
        g[7] = (short)f2bf(bf2f((u16)aE_A[7]) * __expf(argA + pA1.w));
        *reinterpret_cast<short8*>(lds + buf * 8192 + awbyte) = g;
    };
    auto STOREA_B = [&](int buf) {
        short8 g;
        g[0] = (short)f2bf(bf2f((u16)aE_B[0]) * __expf(argB + pB0.x));
        g[1] = (short)f2bf(bf2f((u16)aE_B[1]) * __expf(argB + pB0.y));
        g[2] = (short)f2bf(bf2f((u16)aE_B[2]) * __expf(argB + pB0.z));
        g[3] = (short)f2bf(bf2f((u16)aE_B[3]) * __expf(argB + pB0.w));
        g[4] = (short)f2bf(bf2f((u16)aE_B[4]) * __expf(argB + pB1.x));
        g[5] = (short)f2bf(bf2f((u16)aE_B[5]) * __expf(argB + pB1.y));
        g[6] = (short)f2bf(bf2f((u16)aE_B[6]) * __expf(argB + pB1.z));
        g[7] = (short)f2bf(bf2f((u16)aE_B[7]) * __expf(argB + pB1.w));
        *reinterpret_cast<short8*>(lds + buf * 8192 + awbyte) = g;
    };
    auto BLOAD = [&](int it, short8* b0, short8* b1) {
        #pragma unroll
        for (int n = 0; n < 4; ++n) {
            const int d = wn + n * 16 + (lane & 15);
            const u16* bp = b2t + (size_t)d * TWON + kbase + it * 64 + (lane >> 4) * 8;
            b0[n] = *reinterpret_cast<const short8*>(bp);
            b1[n] = *reinterpret_cast<const short8*>(bp + 32);
        }
    };
    auto DOMFMA = [&](int buf, short8* b0, short8* b1) {
        #pragma unroll
        for (int kk = 0; kk < 2; ++kk) {
            short8 af[4];
            #pragma unroll
            for (int m = 0; m < 4; ++m) {
                const int row = m * 16 + (lane & 15);
                const int off = buf * 8192 + row * 128 +
                                ((kk * 64 + (lane >> 4) * 16) ^ ((row & 7) << 4));
                af[m] = *reinterpret_cast<const short8*>(lds + off);
            }
            #pragma unroll
            for (int m = 0; m < 4; ++m)
                #pragma unroll
                for (int n = 0; n < 4; ++n)
                    acc[m][n] = mfma16b(af[m], (kk == 0) ? b0[n] : b1[n], acc[m][n]);
        }
    };
    // prologue: tile0 in regset A -> buf0; tile1 prefetched into regset B
    LOADA_A(0);
    LOADA_B(1);
    STOREA_A(0);
    __syncthreads();
    for (int it = 0; it < NT; it += 2) {
        // phase 0: compute tile it (buf0); prefetch it+2 (setA); stage it+1 (setB->buf1)
        short8 bfr0[4], bfr1[4];
        BLOAD(it, bfr0, bfr1);                 // B FIRST (oldest vmcnt entries)
        if (it + 2 < NT) LOADA_A(it + 2);      // A-prefetch AFTER B
        DOMFMA(0, bfr0, bfr1);
        STOREA_B(1);                           // tile it+1 (loaded ~1.5 phases ago)
        __syncthreads();
        // phase 1: compute tile it+1 (buf1); prefetch it+3 (setB); stage it+2 (setA->buf0)
        BLOAD(it + 1, bfr0, bfr1);
        if (it + 3 < NT) LOADA_B(it + 3);
        DOMFMA(1, bfr0, bfr1);
        if (it + 2 < NT) STOREA_A(0);
        __syncthreads();
    }
    half_t* pout = part + (size_t)kslice * NN * DD;
    #pragma unroll
    for (int m = 0; m < 4; ++m) {
        float rf[4];
        #pragma unroll
        for (int r4 = 0; r4 < 4; ++r4) rf[r4] = rrs[i0 + m * 16 + (lane >> 4) * 4 + r4];
        #pragma unroll
        for (int n = 0; n < 4; ++n) {
            const int d = wn + n * 16 + (lane & 15);
            #pragma unroll
            for (int r4 = 0; r4 < 4; ++r4) {
                const int i = i0 + m * 16 + (lane >> 4) * 4 + r4;
                pout[(size_t)i * DD + d] = (half_t)(acc[m][n][r4] * rf[r4]);
            }
        }
    }
}

// ---------------- reduce partials (8 f16 slices -> f32 out)
__global__ __launch_bounds__(256)
void reduce_k(const half_t* __restrict__ part, float* __restrict__ out) {
    const size_t e8 = ((size_t)blockIdx.x * 256 + threadIdx.x) * 8;
    float s[8] = {};
    #pragma unroll
    for (int sl = 0; sl < KSLICE; ++sl) {
        half8 v = *reinterpret_cast<const half8*>(part + (size_t)sl * NN * DD + e8);
        #pragma unroll
        for (int q = 0; q < 8; ++q) s[q] += (float)v[q];
    }
    *reinterpret_cast<float4*>(out + e8)     = make_float4(s[0], s[1], s[2], s[3]);
    *reinterpret_cast<float4*>(out + e8 + 4) = make_float4(s[4], s[5], s[6], s[7]);
}

extern "C" void kernel_launch(void* const* d_in, const int* in_sizes, int n_in,
                              void* d_out, int out_size, void* d_ws, size_t ws_size,
                              hipStream_t stream) {
    const float* x = (const float*)d_in[0];
    const float* y = (const float*)d_in[1];
    float* out = (float*)d_out;

    char* w = (char*)d_ws;
    const size_t OFF_EF   = 0;                          // Ef bf16: 64 MiB
    const size_t OFF_BHI  = 67108864;                   // bhi f16: 8 MiB
    const size_t OFF_B2T  = OFF_BHI + 8388608;          // b2t bf16: 8 MiB
    const size_t OFF_PART = OFF_B2T + 8388608;          // part f16: 8 x 4 MiB
    const size_t OFF_RPM  = OFF_PART + 67108864;        // 1 MiB each
    const size_t OFF_RPS  = OFF_RPM + 1048576;
    const size_t OFF_CPM  = OFF_RPS + 1048576;
    const size_t OFF_CPS  = OFF_CPM + 1048576;
    const size_t OFF_CT   = OFF_CPS + 1048576;          // 8 KiB (+pad)
    const size_t OFF_TAIL = OFF_CT + 65536;

    u16*    Ef   = (u16*)(w + OFF_EF);
    half_t* bhi  = (half_t*)(w + OFF_BHI);
    u16*    b2t  = (u16*)(w + OFF_B2T);
    half_t* part = (half_t*)(w + OFF_PART);
    float*  rpm  = (float*)(w + OFF_RPM);
    float*  rps  = (float*)(w + OFF_RPS);
    float*  cpm  = (float*)(w + OFF_CPM);
    float*  cps  = (float*)(w + OFF_CPS);
    float*  Ct   = (float*)(w + OFF_CT);
    float*  nb   = (float*)(w + OFF_TAIL);              // 8192
    float*  rm   = nb  + TWON;                          // 4096
    float*  rrs  = rm  + NN;                            // 4096
    float*  Pj   = rrs + NN;                            // 8192

    prep_k<<<TWON, 64, 0, stream>>>(x, y, bhi, nb);
    gemm1_k<<<dim3(TWON / 128, NN / 128), 256, 0, stream>>>(bhi, nb, Ef, Ct,
                                                            rpm, rps, cpm, cps);
    row_comb_k<<<NN / 256, 256, 0, stream>>>(rpm, rps, rm, rrs);
    col_comb_k<<<TWON / 256, 256, 0, stream>>>(cpm, cps, Pj);
    b2t_k<<<dim3(TWON / 32, DD / 32), dim3(32, 8), 0, stream>>>(x, y, b2t);
    gemm2_k<<<512, 512, 0, stream>>>(Ef, b2t, Ct, rm, Pj, rrs, part);
    reduce_k<<<(NN * DD / 8) / 256, 256, 0, stream>>>(part, out);
}

// Round 14
// 200.458 us; speedup vs baseline: 1.0502x; 1.0502x over previous
//
#include <hip/hip_runtime.h>
#include <math.h>

#define NN   4096
#define DD   512
#define TWON 8192
#define KSLICE 8

typedef _Float16 half_t;
typedef unsigned short u16;
using half8  = __attribute__((ext_vector_type(8))) half_t;
using short8 = __attribute__((ext_vector_type(8))) short;
using f32x4  = __attribute__((ext_vector_type(4))) float;

__device__ __forceinline__ u16 f2bf(float f) {
    unsigned u = __float_as_uint(f);
    u += 0x7fffu + ((u >> 16) & 1u);
    return (u16)(u >> 16);
}
__device__ __forceinline__ float bf2f(u16 h) {
    return __uint_as_float(((unsigned)h) << 16);
}
__device__ __forceinline__ void gl16(const void* g, void* l) {
    __builtin_amdgcn_global_load_lds(
        (const __attribute__((address_space(1))) void*)g,
        (__attribute__((address_space(3))) void*)l, 16, 0, 0);
}
__device__ __forceinline__ f32x4 mfma16h(half8 a, half8 b, f32x4 c) {
    return __builtin_amdgcn_mfma_f32_16x16x32_f16(a, b, c, 0, 0, 0);
}
__device__ __forceinline__ f32x4 mfma16b(short8 a, short8 b, f32x4 c) {
    return __builtin_amdgcn_mfma_f32_16x16x32_bf16(a, b, c, 0, 0, 0);
}

// ---------------- prep: b=[y;x] -> f16 + norms nb[8192]
__global__ __launch_bounds__(64)
void prep_k(const float* __restrict__ x, const float* __restrict__ y,
            half_t* __restrict__ bhi, float* __restrict__ nb) {
    int r = blockIdx.x;           // 0..8191
    int l = threadIdx.x;          // 64
    const float* src = (r < NN) ? (y + (size_t)r * DD) : (x + (size_t)(r - NN) * DD);
    float4 v0 = *reinterpret_cast<const float4*>(src + l * 8);
    float4 v1 = *reinterpret_cast<const float4*>(src + l * 8 + 4);
    float e[8] = {v0.x, v0.y, v0.z, v0.w, v1.x, v1.y, v1.z, v1.w};
    float s = 0.f;
    half8 h;
    #pragma unroll
    for (int q = 0; q < 8; ++q) {
        s += e[q] * e[q];
        h[q] = (half_t)e[q];
    }
    *reinterpret_cast<half8*>(bhi + (size_t)r * DD + l * 8) = h;
    #pragma unroll
    for (int off = 32; off; off >>= 1) s += __shfl_down(s, off);
    if (l == 0) nb[r] = s;
}

// ---------------- b2tr: b2t[d][k] = sign(k) * bhi[k][d] (bf16). bhi and b2t
// are SEPARATE buffers (since r9) — no alias race (round-3 lesson).
__global__ __launch_bounds__(256)
void b2tr_k(const half_t* __restrict__ bhi, u16* __restrict__ b2t) {
    __shared__ half_t tl[32][33];
    int k0 = blockIdx.x * 32, d0 = blockIdx.y * 32;
    int tx = threadIdx.x, ty = threadIdx.y;   // (32,8)
    #pragma unroll
    for (int j = 0; j < 4; ++j)
        tl[ty + 8 * j][tx] = bhi[(size_t)(k0 + ty + 8 * j) * DD + d0 + tx];
    __syncthreads();
    float sgn = (k0 < NN) ? 1.f : -1.f;
    #pragma unroll
    for (int j = 0; j < 4; ++j) {
        float v = (float)tl[tx][ty + 8 * j] * sgn;
        b2t[(size_t)(d0 + ty + 8 * j) * TWON + k0 + tx] = f2bf(v);
    }
}

// ---------------- GEMM1: f16 MFMA + logits; shared-C epilogue (proven r12);
// stores E=exp(l-C) bf16, Ct per tile, rpm/rps row partials, cpm/cps col partials.
__global__ __launch_bounds__(256)
void gemm1_k(const half_t* __restrict__ bhi,
             const float* __restrict__ nb, u16* __restrict__ Ef,
             float* __restrict__ Ct,
             float* __restrict__ rpm, float* __restrict__ rps,
             float* __restrict__ cpm, float* __restrict__ cps) {
    __shared__ unsigned char lds[32768]; // Ahi@0 Bhi@16K, each 128x64 f16 swizzled
    const int t = threadIdx.x;
    const int wave = t >> 6, lane = t & 63;
    const int i0 = blockIdx.y * 128, j0 = blockIdx.x * 128;
    const int wm = (wave >> 1) * 64, wn = (wave & 1) * 64;
    const half_t* ahig = bhi + (size_t)NN * DD;  // x rows are b rows 4096..8191
    f32x4 acc[4][4] = {};
    for (int k0 = 0; k0 < DD; k0 += 64) {
        __syncthreads();
        #pragma unroll
        for (int q = 0; q < 4; ++q) {
            const int dbase = (wave * 4 + q) * 1024;
            const int p  = dbase + lane * 16;
            const int r  = p >> 7;
            const int cb = (p & 127) ^ ((r & 7) << 4);
            const size_t offA = (size_t)(i0 + r) * DD + k0 + (cb >> 1);
            const size_t offB = (size_t)(j0 + r) * DD + k0 + (cb >> 1);
            gl16(ahig + offA, lds + dbase);
            gl16(bhi  + offB, lds + 16384 + dbase);
        }
        asm volatile("s_waitcnt vmcnt(0)" ::: "memory");
        __builtin_amdgcn_sched_barrier(0);
        __syncthreads();
        #pragma unroll
        for (int kk = 0; kk < 2; ++kk) {
            half8 ah[4];
            #pragma unroll
            for (int m = 0; m < 4; ++m) {
                const int row = wm + m * 16 + (lane & 15);
                const int off = row * 128 + ((kk * 64 + (lane >> 4) * 16) ^ ((row & 7) << 4));
                ah[m] = *reinterpret_cast<const half8*>(lds + off);
            }
            #pragma unroll
            for (int n = 0; n < 4; ++n) {
                const int row = wn + n * 16 + (lane & 15);
                const int off = row * 128 + ((kk * 64 + (lane >> 4) * 16) ^ ((row & 7) << 4));
                half8 bh = *reinterpret_cast<const half8*>(lds + 16384 + off);
                #pragma unroll
                for (int m = 0; m < 4; ++m)
                    acc[m][n] = mfma16h(ah[m], bh, acc[m][n]);
            }
        }
    }
    // ---- pass 1: acc -> logits, track thread max
    float nbj[4];
    #pragma unroll
    for (int n = 0; n < 4; ++n) nbj[n] = nb[j0 + wn + n * 16 + (lane & 15)];
    float tmax = -3.0e38f;
    #pragma unroll
    for (int m = 0; m < 4; ++m) {
        #pragma unroll
        for (int r4 = 0; r4 < 4; ++r4) {
            const int i = i0 + wm + m * 16 + (lane >> 4) * 4 + r4;
            const float nxi = nb[NN + i];
            #pragma unroll
            for (int n = 0; n < 4; ++n) {
                const int j = j0 + wn + n * 16 + (lane & 15);
                float sq = nxi + nbj[n] - 2.0f * acc[m][n][r4];
                float lg = -10.0f * sqrtf(fmaxf(sq, 1e-12f));
                if (j == i + NN) lg = -1e7f;
                acc[m][n][r4] = lg;
                tmax = fmaxf(tmax, lg);
            }
        }
    }
    // ---- block-wide shared max C
    #pragma unroll
    for (int off = 1; off < 64; off <<= 1) tmax = fmaxf(tmax, __shfl_xor(tmax, off));
    __syncthreads();
    float* red = reinterpret_cast<float*>(lds);
    if (lane == 0) red[wave] = tmax;
    __syncthreads();
    const float C = fmaxf(fmaxf(red[0], red[1]), fmaxf(red[2], red[3]));
    __syncthreads();
    if (t == 0) Ct[blockIdx.y * 64 + blockIdx.x] = C;
    // ---- pass 2: single exp; store bf16 E; row/col partial sums (pure adds)
    float rs[16] = {}, cs[4] = {};
    #pragma unroll
    for (int m = 0; m < 4; ++m)
        #pragma unroll
        for (int r4 = 0; r4 < 4; ++r4) {
            const int idx = m * 4 + r4;
            const int i = i0 + wm + m * 16 + (lane >> 4) * 4 + r4;
            #pragma unroll
            for (int n = 0; n < 4; ++n) {
                const int j = j0 + wn + n * 16 + (lane & 15);
                float e = __expf(acc[m][n][r4] - C);
                Ef[(size_t)i * TWON + j] = f2bf(e);
                rs[idx] += e;
                cs[n]   += e;
            }
        }
    #pragma unroll
    for (int off = 1; off < 16; off <<= 1) {
        #pragma unroll
        for (int idx = 0; idx < 16; ++idx) rs[idx] += __shfl_xor(rs[idx], off);
    }
    #pragma unroll
    for (int off = 16; off < 64; off <<= 1) {
        #pragma unroll
        for (int n = 0; n < 4; ++n) cs[n] += __shfl_xor(cs[n], off);
    }
    // ---- cross-wave combine: rows red[0..255], cols red[256..511]
    if ((lane & 15) == 0) {
        #pragma unroll
        for (int m = 0; m < 4; ++m)
            #pragma unroll
            for (int r4 = 0; r4 < 4; ++r4) {
                const int r = wm + m * 16 + (lane >> 4) * 4 + r4;
                red[(wave & 1) * 128 + r] = rs[m * 4 + r4];
            }
    }
    if (lane < 16) {
        #pragma unroll
        for (int n = 0; n < 4; ++n) {
            const int c = wn + n * 16 + lane;
            red[256 + (wave >> 1) * 128 + c] = cs[n];
        }
    }
    __syncthreads();
    if (t < 128) {
        float S = red[t] + red[128 + t];
        rpm[(size_t)blockIdx.x * NN + i0 + t] = C;
        rps[(size_t)blockIdx.x * NN + i0 + t] = S;
    } else {
        const int c = t - 128;
        float S = red[256 + c] + red[384 + c];
        cpm[(size_t)blockIdx.y * TWON + j0 + c] = C;
        cps[(size_t)blockIdx.y * TWON + j0 + c] = S;
    }
}

// ---------------- combine row partials (64 j-tiles, online) -> rm, rrs
__global__ __launch_bounds__(256)
void row_comb_k(const float* __restrict__ rpm, const float* __restrict__ rps,
                float* __restrict__ rm, float* __restrict__ rrs) {
    int i = blockIdx.x * 256 + threadIdx.x;
    float M = -3.0e38f;
    for (int tt = 0; tt < TWON / 128; ++tt) M = fmaxf(M, rpm[(size_t)tt * NN + i]);
    float S = 0.f;
    for (int tt = 0; tt < TWON / 128; ++tt)
        S += rps[(size_t)tt * NN + i] * __expf(rpm[(size_t)tt * NN + i] - M);
    rm[i] = M; rrs[i] = rsqrtf(S);
}

// ---------------- combine col partials (32 i-tiles) -> Pj = -cm/2 + ln(rcs)
__global__ __launch_bounds__(256)
void col_comb_k(const float* __restrict__ cpm, const float* __restrict__ cps,
                float* __restrict__ Pj) {
    int j = blockIdx.x * 256 + threadIdx.x;
    float M = -3.0e38f;
    for (int tt = 0; tt < NN / 128; ++tt) M = fmaxf(M, cpm[(size_t)tt * TWON + j]);
    float S = 0.f;
    for (int tt = 0; tt < NN / 128; ++tt)
        S += cps[(size_t)tt * TWON + j] * __expf(cpm[(size_t)tt * TWON + j] - M);
    Pj[j] = -0.5f * M - 0.5f * logf(S);    // = -cm/2 + ln(rcs)
}

// ---------------- GEMM2: split-K(8), fused-transform reg-staged A (bf16),
// dbuf LDS; B frags issued FIRST each phase (counted vmcnt). r12-proven loop.
// Epilogue: packed-bf16 raw-order partials, fully coalesced 128B/lane.
__global__ __launch_bounds__(512, 4)
void gemm2_k(const u16* __restrict__ Ef, const u16* __restrict__ b2t,
             const float* __restrict__ Ct, const float* __restrict__ rm,
             const float* __restrict__ Pj, const float* __restrict__ rrs,
             unsigned* __restrict__ part) {
    __shared__ unsigned char lds[16384];   // 2 x (64x64 bf16 A tile, swizzled)
    const int t = threadIdx.x;
    const int wave = t >> 6, lane = t & 63;
    const int sw = blockIdx.x;             // 0..511
    const int kslice = sw & 7;             // one kslice per XCD
    const int i0 = (sw >> 3) * 64;
    const int ib = (sw >> 3) >> 1;         // gemm1 128-row tile index
    const int kbase = kslice * (TWON / KSLICE);   // *1024
    const int wn = wave * 64;
    const int sr = t >> 3;          // staging row 0..63
    const int kc = (t & 7) * 8;     // staging k-offset (elements)
    const int awbyte = sr * 128 + ((kc * 2) ^ ((sr & 7) << 4));
    const int NT = (TWON / KSLICE) / 64;   // 16
    const float rmh = 0.5f * rm[i0 + sr];
    f32x4 acc[4][4] = {};
    short8 aE;
    float4 p0, p1;
    float arg;
    auto LOADA = [&](int it) {
        const int k = kbase + it * 64 + kc;
        aE = *reinterpret_cast<const short8*>(Ef + (size_t)(i0 + sr) * TWON + k);
        p0 = *reinterpret_cast<const float4*>(Pj + k);
        p1 = *reinterpret_cast<const float4*>(Pj + k + 4);
        arg = Ct[ib * 64 + ((kbase + it * 64) >> 7)] - rmh;
    };
    auto STOREA = [&](int buf) {
        short8 g;
        g[0] = (short)f2bf(bf2f((u16)aE[0]) * __expf(arg + p0.x));
        g[1] = (short)f2bf(bf2f((u16)aE[1]) * __expf(arg + p0.y));
        g[2] = (short)f2bf(bf2f((u16)aE[2]) * __expf(arg + p0.z));
        g[3] = (short)f2bf(bf2f((u16)aE[3]) * __expf(arg + p0.w));
        g[4] = (short)f2bf(bf2f((u16)aE[4]) * __expf(arg + p1.x));
        g[5] = (short)f2bf(bf2f((u16)aE[5]) * __expf(arg + p1.y));
        g[6] = (short)f2bf(bf2f((u16)aE[6]) * __expf(arg + p1.z));
        g[7] = (short)f2bf(bf2f((u16)aE[7]) * __expf(arg + p1.w));
        *reinterpret_cast<short8*>(lds + buf * 8192 + awbyte) = g;
    };
    LOADA(0);
    STOREA(0);
    __syncthreads();
    int cur = 0;
    for (int it = 0; it < NT; ++it) {
        // B fragments FIRST (oldest vmcnt entries -> counted wait, not drain)
        short8 bfr0[4], bfr1[4];
        #pragma unroll
        for (int n = 0; n < 4; ++n) {
            const int d = wn + n * 16 + (lane & 15);
            const u16* bp = b2t + (size_t)d * TWON + kbase + it * 64 + (lane >> 4) * 8;
            bfr0[n] = *reinterpret_cast<const short8*>(bp);
            bfr1[n] = *reinterpret_cast<const short8*>(bp + 32);
        }
        if (it + 1 < NT) LOADA(it + 1);    // next-A issue (consumed after MFMA)
        #pragma unroll
        for (int kk = 0; kk < 2; ++kk) {
            short8 af[4];
            #pragma unroll
            for (int m = 0; m < 4; ++m) {
                const int row = m * 16 + (lane & 15);
                const int off = cur * 8192 + row * 128 +
                                ((kk * 64 + (lane >> 4) * 16) ^ ((row & 7) << 4));
                af[m] = *reinterpret_cast<const short8*>(lds + off);
            }
            #pragma unroll
            for (int m = 0; m < 4; ++m)
                #pragma unroll
                for (int n = 0; n < 4; ++n)
                    acc[m][n] = mfma16b(af[m], (kk == 0) ? bfr0[n] : bfr1[n], acc[m][n]);
        }
        if (it + 1 < NT) STOREA(cur ^ 1);  // transform + stage into other buffer
        __syncthreads();
        cur ^= 1;
    }
    // ---- epilogue: pack acc*rrs to bf16 pairs, raw lane-order coalesced store
    unsigned* pout = part + ((size_t)(kslice * 64 + (sw >> 3)) * 512 + t) * 32;
    #pragma unroll
    for (int m = 0; m < 4; ++m) {
        float rf[4];
        #pragma unroll
        for (int r4 = 0; r4 < 4; ++r4) rf[r4] = rrs[i0 + m * 16 + (lane >> 4) * 4 + r4];
        unsigned pk[8];
        #pragma unroll
        for (int n = 0; n < 4; ++n) {
            pk[n * 2]     = (unsigned)f2bf(acc[m][n][0] * rf[0]) |
                            ((unsigned)f2bf(acc[m][n][1] * rf[1]) << 16);
            pk[n * 2 + 1] = (unsigned)f2bf(acc[m][n][2] * rf[2]) |
                            ((unsigned)f2bf(acc[m][n][3] * rf[3]) << 16);
        }
        *reinterpret_cast<uint4*>(pout + m * 8)     = *reinterpret_cast<uint4*>(pk);
        *reinterpret_cast<uint4*>(pout + m * 8 + 4) = *reinterpret_cast<uint4*>(pk + 4);
    }
}

// ---------------- reduce: sum 8 packed-bf16 raw-order slices -> out[i][d] f32
__global__ __launch_bounds__(512)
void reduce_k(const unsigned* __restrict__ part, float* __restrict__ out) {
    const int b = blockIdx.x;            // 0..255
    const int iblk = b >> 2, mq = b & 3;
    const int t = threadIdx.x;
    const int lane = t & 63, wave = t >> 6;
    float s[16] = {};
    #pragma unroll
    for (int ks = 0; ks < KSLICE; ++ks) {
        const unsigned* p = part + ((size_t)(ks * 64 + iblk) * 512 + t) * 32 + mq * 8;
        uint4 a = *reinterpret_cast<const uint4*>(p);
        uint4 c = *reinterpret_cast<const uint4*>(p + 4);
        unsigned u[8] = {a.x, a.y, a.z, a.w, c.x, c.y, c.z, c.w};
        #pragma unroll
        for (int n = 0; n < 4; ++n) {
            s[n * 4 + 0] += bf2f((u16)(u[n * 2] & 0xffffu));
            s[n * 4 + 1] += bf2f((u16)(u[n * 2] >> 16));
            s[n * 4 + 2] += bf2f((u16)(u[n * 2 + 1] & 0xffffu));
            s[n * 4 + 3] += bf2f((u16)(u[n * 2 + 1] >> 16));
        }
    }
    #pragma unroll
    for (int n = 0; n < 4; ++n)
        #pragma unroll
        for (int r4 = 0; r4 < 4; ++r4) {
            const int i = iblk * 64 + mq * 16 + (lane >> 4) * 4 + r4;
            const int d = wave * 64 + n * 16 + (lane & 15);
            out[(size_t)i * DD + d] = s[n * 4 + r4];
        }
}

extern "C" void kernel_launch(void* const* d_in, const int* in_sizes, int n_in,
                              void* d_out, int out_size, void* d_ws, size_t ws_size,
                              hipStream_t stream) {
    const float* x = (const float*)d_in[0];
    const float* y = (const float*)d_in[1];
    float* out = (float*)d_out;

    char* w = (char*)d_ws;
    const size_t OFF_EF   = 0;                          // Ef bf16: 64 MiB
    const size_t OFF_BHI  = 67108864;                   // bhi f16: 8 MiB
    const size_t OFF_B2T  = OFF_BHI + 8388608;          // b2t bf16: 8 MiB
    const size_t OFF_PART = OFF_B2T + 8388608;          // part packed bf16: 32 MiB
    const size_t OFF_RPM  = OFF_PART + 67108864;        // 1 MiB each
    const size_t OFF_RPS  = OFF_RPM + 1048576;
    const size_t OFF_CPM  = OFF_RPS + 1048576;
    const size_t OFF_CPS  = OFF_CPM + 1048576;
    const size_t OFF_CT   = OFF_CPS + 1048576;          // 8 KiB (+pad)
    const size_t OFF_TAIL = OFF_CT + 65536;

    u16*      Ef   = (u16*)(w + OFF_EF);
    half_t*   bhi  = (half_t*)(w + OFF_BHI);
    u16*      b2t  = (u16*)(w + OFF_B2T);
    unsigned* part = (unsigned*)(w + OFF_PART);
    float*    rpm  = (float*)(w + OFF_RPM);
    float*    rps  = (float*)(w + OFF_RPS);
    float*    cpm  = (float*)(w + OFF_CPM);
    float*    cps  = (float*)(w + OFF_CPS);
    float*    Ct   = (float*)(w + OFF_CT);
    float*    nb   = (float*)(w + OFF_TAIL);            // 8192
    float*    rm   = nb  + TWON;                        // 4096
    float*    rrs  = rm  + NN;                          // 4096
    float*    Pj   = rrs + NN;                          // 8192

    prep_k<<<TWON, 64, 0, stream>>>(x, y, bhi, nb);
    gemm1_k<<<dim3(TWON / 128, NN / 128), 256, 0, stream>>>(bhi, nb, Ef, Ct,
                                                            rpm, rps, cpm, cps);
    row_comb_k<<<NN / 256, 256, 0, stream>>>(rpm, rps, rm, rrs);
    col_comb_k<<<TWON / 256, 256, 0, stream>>>(cpm, cps, Pj);
    b2tr_k<<<dim3(TWON / 32, DD / 32), dim3(32, 8), 0, stream>>>(bhi, b2t);
    gemm2_k<<<512, 512, 0, stream>>>(Ef, b2t, Ct, rm, Pj, rrs, part);
    reduce_k<<<256, 512, 0, stream>>>(part, out);
}